// Round 8
// baseline (84.164 us; speedup 1.0000x reference)
//
#include <hip/hip_runtime.h>

// probs = |U^{x8} f|^2 / ||f||^2, U = 8x8 complex gate on each of 8 qubit triples.
// MFMA: per 3-qubit axis, D = A*B, A(16x16 f16) = [[Gr,-Gi],[Gi,Gr]], B = 16
// rest-columns of [Xr;Xi], f32 accumulate (v_mfma_f32_16x16x16_f16).
//
// Round-7 structure with ONE scheduling change (no layout/formula changes):
//   k_pass1 grid 512x1024 -> 256x1024, 2 tiles per block. Tile 1's eight
//   float4 global loads are issued right after tile 0's fill barrier and held
//   in VGPRs across tile 0's stages/writeout (HBM latency hidden under
//   ~15us of compute). LDS reuse between tiles is protected by an lgkm-only
//   raw s_barrier (no vmcnt drain -> tile-0 stores + nothing else pending;
//   prefetch loads are OLDER than the stores in the vmcnt queue, so the
//   compiler's automatic wait on load-use does not drain the stores).
//
// k_pass1: axes A3..A7 (low 15 bits). 128KB LDS tile, 5 MFMA stages (uniform
//   digit rotation on layout [e3|e2|e1|e0|p|k], swizzle SW1); fill writes re
//   plane only (A3 reads im as 0), fuses ||f||^2 partials -> d_ws[tile];
//   stage A7 fused with writeout of interleaved (re,im) f16 intermediate.
// k_pass2: axes A0..A2. 2048 blocks x 256 thr, 32KB LDS (512 hi x 16 lo),
//   layout [s1|s0|sp|p|k] with swizzle SW2; 2 LDS stages + final stage fused
//   with probs = (re^2+im^2)*inv writeout. Each block reads/writes the same
//   private region of d_out -> race-free.

typedef _Float16 f16;
typedef _Float16 f16x4 __attribute__((ext_vector_type(4)));
typedef float f32x4 __attribute__((ext_vector_type(4)));
typedef unsigned int u32;
typedef unsigned short u16;

__device__ __forceinline__ u32 SW1(u32 a) { return a ^ (((a >> 8) & 0xFu) << 3); }
__device__ __forceinline__ u32 SW2(u32 a) { return a ^ (((a >> 7) & 0x7u) << 4); }

__device__ __forceinline__ u32 PK(float x, float y) {
  return __builtin_bit_cast(u32, __builtin_amdgcn_cvt_pkrtz(x, y));
}

#define BARRIER_RAW()                                   \
  do {                                                  \
    asm volatile("s_waitcnt lgkmcnt(0)" ::: "memory");  \
    __builtin_amdgcn_sched_barrier(0);                  \
    __builtin_amdgcn_s_barrier();                       \
  } while (0)

// A fragment for v_mfma_f32_16x16x16_f16: lane holds A[row=l&15][k=(l>>4)*4+e].
// A = [[Gr, -Gi], [Gi, Gr]]; rows 0-7 -> re out, 8-15 -> im out; k<8 hits Xr.
__device__ __forceinline__ f16x4 build_A(const float* __restrict__ gr,
                                         const float* __restrict__ gi, int l) {
  const int row = l & 15, kg = l >> 4;
  const int pg = row & 7, rpl = row >> 3, kpl = kg >> 1;
  f16x4 a;
#pragma unroll
  for (int e = 0; e < 4; ++e) {
    const int j = (kg & 1) * 4 + e;
    const float grv = gr[pg * 8 + j], giv = gi[pg * 8 + j];
    const float v = rpl == 0 ? (kpl == 0 ? grv : -giv) : (kpl == 0 ? giv : grv);
    a[e] = (f16)v;
  }
  return a;
}

__device__ __forceinline__ f32x4 MF(f16x4 A, uint2 bw, f32x4 C) {
  return __builtin_amdgcn_mfma_f32_16x16x16f16(A, __builtin_bit_cast(f16x4, bw),
                                               C, 0, 0, 0);
}

// One in-LDS gate stage (read all -> barrier -> write all -> barrier).
// FIRST=true: im-plane (kg>=2) reads replaced by 0 (fill wrote re only).
template <bool FIRST>
__device__ __forceinline__ void lds_stage(char* lb, f16x4 A, int w, int l) {
  const int kg = l >> 4, c = l & 15, c3 = c >> 3, p = kg >> 1;
  const u32 rb = (u32)(w * 512 + c * 32 + kg * 8);
  const f32x4 Z = {0.f, 0.f, 0.f, 0.f};
  f32x4 acc[16];
#pragma unroll
  for (int g = 0; g < 4; ++g) {
#pragma unroll
    for (int m = 0; m < 4; ++m) {
      const int j = (g & 1) + m * 2 + (g >> 1) * 8;
      uint2 bw = make_uint2(0u, 0u);
      if (!FIRST || kg < 2)
        bw = *(const uint2*)(lb + SW1(rb + (u32)j * 8192u));
      acc[g * 4 + m] = MF(A, bw, Z);
    }
  }
  __syncthreads();  // all reads everywhere done -> in-place writes safe
  const u32 wl = (u32)(((w >> 2) << 14) + (((w & 3) * 2 + c3) << 11) +
                       ((c & 7) << 8) + ((kg & 1) << 7) + (p << 4));
#pragma unroll
  for (int g = 0; g < 4; ++g) {
#pragma unroll
    for (int rr = 0; rr < 4; ++rr) {
      const u32 d0 = PK(acc[g * 4 + 0][rr], acc[g * 4 + 1][rr]);
      const u32 d1 = PK(acc[g * 4 + 2][rr], acc[g * 4 + 3][rr]);
      const u32 lg = wl + (u32)(((g & 1) << 16) + ((g >> 1) << 3) + (rr << 5));
      *(uint2*)(lb + SW1(lg)) = make_uint2(d0, d1);
    }
  }
  __syncthreads();
}

// fill L(0): [A4|A5|A6|A7|p|A3], re plane only, from 8 pre-loaded float4s;
// returns this thread's ||f||^2 partial.
__device__ __forceinline__ float p1_fill(char* lb, const float4* vv, int t) {
  float s = 0.f;
#pragma unroll
  for (int d = 0; d < 8; ++d)
    s += vv[d].x * vv[d].x + vv[d].y * vv[d].y + vv[d].z * vv[d].z +
         vv[d].w * vv[d].w;
  const u32 fl = (u32)(((t >> 7) << 14) + (((t >> 4) & 7) << 11) +
                       (((t >> 1) & 7) << 8) + ((t & 1) << 7));
#pragma unroll
  for (int g2 = 0; g2 < 2; ++g2) {
#pragma unroll
    for (int q = 0; q < 4; ++q) {
      const float a0 = q == 0 ? vv[g2 * 4 + 0].x : q == 1 ? vv[g2 * 4 + 0].y
                     : q == 2 ? vv[g2 * 4 + 0].z : vv[g2 * 4 + 0].w;
      const float a1 = q == 0 ? vv[g2 * 4 + 1].x : q == 1 ? vv[g2 * 4 + 1].y
                     : q == 2 ? vv[g2 * 4 + 1].z : vv[g2 * 4 + 1].w;
      const float a2 = q == 0 ? vv[g2 * 4 + 2].x : q == 1 ? vv[g2 * 4 + 2].y
                     : q == 2 ? vv[g2 * 4 + 2].z : vv[g2 * 4 + 2].w;
      const float a3 = q == 0 ? vv[g2 * 4 + 3].x : q == 1 ? vv[g2 * 4 + 3].y
                     : q == 2 ? vv[g2 * 4 + 3].z : vv[g2 * 4 + 3].w;
      const u32 lg = fl + (u32)((q << 5) + (g2 << 3));
      *(uint2*)(lb + SW1(lg)) = make_uint2(PK(a0, a1), PK(a2, a3));
      // im plane intentionally NOT written (stage A3 reads it as 0)
    }
  }
  return s;
}

// stages A3..A6 + stage A7 fused with intermediate writeout.
__device__ __forceinline__ void p1_tile(char* lb, f16x4 A, int w, int l,
                                        uint4* __restrict__ st, int tile) {
  lds_stage<true>(lb, A, w, l);   // A3 (im read as 0)
  lds_stage<false>(lb, A, w, l);  // A4
  lds_stage<false>(lb, A, w, l);  // A5
  lds_stage<false>(lb, A, w, l);  // A6
  // L4 = [A3|A4|A5|A6|p|A7]: A3=j>>1, A4=(j&1)*4+(w>>2), A5=(w&3)*2+c3, A6=c&7
  const int kg = l >> 4, c = l & 15, c3 = c >> 3, p = kg >> 1;
  const f32x4 Z = {0.f, 0.f, 0.f, 0.f};
  const u32 rb = (u32)(w * 512 + c * 32 + kg * 8);
  const size_t ob = (size_t)tile * 8192;  // uint4 units
#pragma unroll
  for (int j = 0; j < 16; ++j) {
    const uint2 bw = *(const uint2*)(lb + SW1(rb + (u32)j * 8192u));
    const f32x4 a = MF(A, bw, Z);
    const u32 h01 = PK(a[0], a[1]), h23 = PK(a[2], a[3]);
    const u32 q01 = __shfl_xor(h01, 32, 64), q23 = __shfl_xor(h23, 32, 64);
    if (p == 0) {  // partner (p=1) holds im parts
      const int A3 = j >> 1, A4 = (j & 1) * 4 + (w >> 2), A5 = (w & 3) * 2 + c3;
      uint4 vv;
      vv.x = (h01 & 0xffffu) | (q01 << 16);
      vv.y = (h01 >> 16) | (q01 & 0xffff0000u);
      vv.z = (h23 & 0xffffu) | (q23 << 16);
      vv.w = (h23 >> 16) | (q23 & 0xffff0000u);
      st[ob + (u32)(((A3 * 64 + A4 * 8 + A5) << 4) + ((c & 7) << 1) + (kg & 1))] = vv;
    }
  }
}

__global__ __launch_bounds__(1024, 4) void k_pass1(
    const float* __restrict__ f, const float* __restrict__ gr,
    const float* __restrict__ gi, uint4* __restrict__ st,
    float* __restrict__ wsp) {
  __shared__ __align__(16) char lb[131072];
  __shared__ float red[16];
  const int t = threadIdx.x, l = t & 63, w = t >> 6, blk = blockIdx.x;
  const f16x4 A = build_A(gr, gi, l);
  const float4* fin = (const float4*)f + (size_t)(2 * blk) * 8192;

  // ---- tile 0: load + fill + norm partial ----
  float4 vv[8];
#pragma unroll
  for (int d = 0; d < 8; ++d) vv[d] = fin[d * 1024 + t];
  float s = p1_fill(lb, vv, t);
#pragma unroll
  for (int off = 32; off; off >>= 1) s += __shfl_down(s, off, 64);
  if (l == 0) red[w] = s;
  __syncthreads();  // fill + red visible
  if (t == 0) {
    float a = 0.f;
#pragma unroll
    for (int i = 0; i < 16; ++i) a += red[i];
    wsp[2 * blk] = a;
  }

  // ---- prefetch tile 1 (held in VGPRs across tile 0's compute) ----
  float4 pv[8];
#pragma unroll
  for (int d = 0; d < 8; ++d) pv[d] = fin[8192 + d * 1024 + t];

  p1_tile(lb, A, w, l, st, 2 * blk);  // tile 0 stages + writeout

  // lgkm-only barrier: all tile-0 LDS reads done; prefetch loads & tile-0
  // stores stay in flight (loads are older in the vmcnt queue than stores).
  BARRIER_RAW();

  // ---- tile 1: fill from prefetched regs + norm partial ----
  s = p1_fill(lb, pv, t);
#pragma unroll
  for (int off = 32; off; off >>= 1) s += __shfl_down(s, off, 64);
  if (l == 0) red[w] = s;
  __syncthreads();
  if (t == 0) {
    float a = 0.f;
#pragma unroll
    for (int i = 0; i < 16; ++i) a += red[i];
    wsp[2 * blk + 1] = a;
  }

  p1_tile(lb, A, w, l, st, 2 * blk + 1);  // tile 1 stages + writeout
}

// ---------------- pass2: 32KB tile, 4 waves (round-4 verbatim) ----------------
// halfword layout h = s1*2048 + s0*256 + sp*16 + p*8 + k  (byte = 2h, SW2).
// L0: k=A2,s0=A0,s1=A1 -> stage A2 -> L1: k=A1,s0=A2,s1=A0 -> stage A1 ->
// L2: k=A0,s0=A1,s1=A2 -> final stage A0 + probs.
__device__ __forceinline__ void p2_stage(char* lb, f16x4 A, int w, int l) {
  const int kg = l >> 4, c = l & 15, pp = kg >> 1;
  const f32x4 Z = {0.f, 0.f, 0.f, 0.f};
  f32x4 acc[16];
#pragma unroll
  for (int g = 0; g < 4; ++g) {
#pragma unroll
    for (int m = 0; m < 4; ++m) {
      const int j = (g & 1) + m * 2 + (g >> 1) * 8;
      const u32 rb = (u32)(j * 2048 + w * 512 + c * 32 + kg * 8);
      const uint2 bw = *(const uint2*)(lb + SW2(rb));
      acc[g * 4 + m] = MF(A, bw, Z);
    }
  }
  __syncthreads();
  // packed b128 writes: for (pe,rr), halfword slots k'=j>>1 are consecutive
#pragma unroll
  for (int pe = 0; pe < 2; ++pe) {
#pragma unroll
    for (int rr = 0; rr < 4; ++rr) {
      uint4 vv;
      vv.x = PK(acc[pe * 4 + 0][rr], acc[pe * 4 + 1][rr]);
      vv.y = PK(acc[pe * 4 + 2][rr], acc[pe * 4 + 3][rr]);
      vv.z = PK(acc[(2 + pe) * 4 + 0][rr], acc[(2 + pe) * 4 + 1][rr]);
      vv.w = PK(acc[(2 + pe) * 4 + 2][rr], acc[(2 + pe) * 4 + 3][rr]);
      const u32 wb = (u32)((pe * 4 + w) * 4096 + ((kg & 1) * 4 + rr) * 512 +
                           c * 32 + pp * 16);
      *(uint4*)(lb + SW2(wb)) = vv;
    }
  }
  __syncthreads();
}

__global__ __launch_bounds__(256, 4) void k_pass2(
    const uint4* gp, const float* __restrict__ gr, const float* __restrict__ gi,
    const float* __restrict__ wsp, float* out) {
  __shared__ __align__(16) char lb[32768];
  __shared__ float red[4];
  const int t = threadIdx.x, l = t & 63, w = t >> 6;
  const int kg = l >> 4, c = l & 15, pp = kg >> 1;
  const int b9 = blockIdx.x >> 2, q = blockIdx.x & 3;
  const f16x4 A = build_A(gr, gi, l);
  const f32x4 Z = {0.f, 0.f, 0.f, 0.f};

  // norm: reduce pass1 partials (deterministic)
  float sp_ = wsp[t] + wsp[t + 256];
#pragma unroll
  for (int off = 32; off; off >>= 1) sp_ += __shfl_down(sp_, off, 64);
  if (l == 0) red[w] = sp_;

  // ---- fill: 4-hi-grouped uint4 reads -> packed b64 plane writes ----
  // element n = hi*2^15 + b9*64 + q*16 + sp; uint4 idx = hi*8192 + b9*16 + q*4 + u
  {
    const int z = t >> 2, u = t & 3;
    const int A1 = z & 7, A0 = z >> 3;
#pragma unroll
    for (int a2g = 0; a2g < 2; ++a2g) {
      uint4 raw[4];
#pragma unroll
      for (int d = 0; d < 4; ++d)
        raw[d] = gp[(size_t)(z * 8 + 4 * a2g + d) * 8192 + (u32)(b9 * 16 + q * 4 + u)];
#pragma unroll
      for (int v = 0; v < 4; ++v) {
        const u32 w0 = v == 0 ? raw[0].x : v == 1 ? raw[0].y : v == 2 ? raw[0].z : raw[0].w;
        const u32 w1 = v == 0 ? raw[1].x : v == 1 ? raw[1].y : v == 2 ? raw[1].z : raw[1].w;
        const u32 w2 = v == 0 ? raw[2].x : v == 1 ? raw[2].y : v == 2 ? raw[2].z : raw[2].w;
        const u32 w3 = v == 0 ? raw[3].x : v == 1 ? raw[3].y : v == 2 ? raw[3].z : raw[3].w;
        const int sp = u * 4 + v;
        const u32 base = (u32)(A1 * 4096 + A0 * 512 + sp * 32 + 8 * a2g);
        // re plane (p=0): lo halves, k = A2 = 4*a2g + d consecutive
        *(uint2*)(lb + SW2(base)) =
            make_uint2((w0 & 0xffffu) | (w1 << 16), (w2 & 0xffffu) | (w3 << 16));
        // im plane (p=1)
        *(uint2*)(lb + SW2(base + 16u)) =
            make_uint2((w0 >> 16) | (w1 & 0xffff0000u), (w2 >> 16) | (w3 & 0xffff0000u));
      }
    }
  }
  __syncthreads();
  const float inv = 1.0f / (red[0] + red[1] + red[2] + red[3]);

  p2_stage(lb, A, w, l);  // A2
  p2_stage(lb, A, w, l);  // A1

  // ---- final stage A0 + probs writeout ----
  // L2: A2 = j>>1, A1 = (j&1)*4+w, sp = c; rows: p=kg>>1, A0 = (kg&1)*4+rr
#pragma unroll
  for (int j = 0; j < 16; ++j) {
    const u32 rb = (u32)(j * 2048 + w * 512 + c * 32 + kg * 8);
    const uint2 bw = *(const uint2*)(lb + SW2(rb));
    const f32x4 a = MF(A, bw, Z);
    const int A2 = j >> 1, A1 = (j & 1) * 4 + w;
    const size_t gb = ((size_t)A1 << 18) + ((size_t)A2 << 15) +
                      (u32)(b9 * 64 + q * 16 + c);
#pragma unroll
    for (int rr = 0; rr < 4; ++rr) {
      float qv = a[rr] * a[rr];
      qv += __shfl_xor(qv, 32, 64);  // re^2 + im^2 from partner plane
      if ((rr >> 1) == pp) {         // p=0 stores rr 0,1; p=1 stores rr 2,3
        const size_t A0 = (size_t)((kg & 1) * 4 + rr);
        out[gb + (A0 << 21)] = qv * inv;
      }
    }
  }
}

extern "C" void kernel_launch(void* const* d_in, const int* in_sizes, int n_in,
                              void* d_out, int out_size, void* d_ws,
                              size_t ws_size, hipStream_t stream) {
  (void)in_sizes; (void)n_in; (void)out_size; (void)ws_size;
  const float* f = (const float*)d_in[0];
  const float* gr = (const float*)d_in[1];
  const float* gi = (const float*)d_in[2];
  float* wsp = (float*)d_ws;  // 512 floats

  k_pass1<<<dim3(256), dim3(1024), 0, stream>>>(f, gr, gi, (uint4*)d_out, wsp);
  k_pass2<<<dim3(2048), dim3(256), 0, stream>>>((const uint4*)d_out, gr, gi,
                                                wsp, (float*)d_out);
}